// Round 5
// baseline (2650.576 us; speedup 1.0000x reference)
//
#include <hip/hip_runtime.h>
#include <stdint.h>
#include <math.h>

// Problem constants (B, H, T) = (16, 2048, 512)
#define Hdim   2048
#define Bdim   16
#define Tsteps 512
#define NWG    64    // workgroups; each owns KC columns of h  (halved vs R3)
#define TPB    256   // 4 waves
#define KC     32    // h-columns per WG  (NWG*KC == Hdim)
#define NCHUNK 16    // K-chunks of 32 per wave (wave K-range = 512)
#define FLAGSTRIDE 32  // uint32s between per-WG flags (128B) — separate lines
#define HBYTES (Bdim * Hdim * 2)   // one h buffer in bytes (fragment-major bf16)

typedef __attribute__((ext_vector_type(8))) short short8_t;  // 8 bf16 (4 VGPRs)
typedef __attribute__((ext_vector_type(4))) float f32x4;     // MFMA C/D
typedef __attribute__((ext_vector_type(4))) unsigned int u32x4;

__device__ __forceinline__ short f2bf(float x) {
  uint32_t u = __builtin_bit_cast(uint32_t, x);
  u += 0x7fffu + ((u >> 16) & 1u);   // RNE
  return (short)(u >> 16);
}

__device__ __forceinline__ short8_t load8_bf(const float* __restrict__ p) {
  short8_t r;
#pragma unroll
  for (int j = 0; j < 8; ++j) r[j] = f2bf(p[j]);
  return r;
}

// ---- flag barrier helpers (R3-proven protocol) ----
__device__ __forceinline__ void publish(uint32_t* flags, int wg, int tid, uint32_t n) {
  asm volatile("s_waitcnt vmcnt(0)" ::: "memory");   // drain h/part stores
  __syncthreads();
  if (tid == 0)
    __hip_atomic_store(flags + wg * FLAGSTRIDE, n, __ATOMIC_RELAXED, __HIP_MEMORY_SCOPE_AGENT);
}
__device__ __forceinline__ void waitall(const uint32_t* flags, int tid, uint32_t n) {
  if (tid < NWG) {
    while (__hip_atomic_load(flags + tid * FLAGSTRIDE, __ATOMIC_RELAXED,
                             __HIP_MEMORY_SCOPE_AGENT) < n) {
      __builtin_amdgcn_s_sleep(1);
    }
  }
  __syncthreads();
}

// ---- h buffer layout (unchanged from R3): MFMA-fragment-major ----
// 16B block (gc*4 + quad)*16 + batch holds cols [gc*32+quad*8, +8) of one batch.
// Byte offset of (b, col): (col>>3)*256 + b*16 + (col&7)*2.
// Consumer wave reads per chunk a contiguous 1KB span (lane*16B), uncached.
__device__ __forceinline__ void publish_h(uint32_t* hbuf32, int buf,
                                          int eb, int ekc, int ecol, float h_own) {
  uint32_t mybits = (uint32_t)(uint16_t)f2bf(h_own);
  uint32_t n1 = (uint32_t)__shfl_xor((int)mybits, 1, 64);
  uint32_t a  = (mybits & 0xffffu) | (n1 << 16);
  uint32_t b  = (uint32_t)__shfl_xor((int)a, 2, 64);
  uint32_t c4 = (uint32_t)__shfl_xor((int)a, 4, 64);
  uint32_t d  = (uint32_t)__shfl_xor((int)b, 4, 64);
  if ((ekc & 7) == 0) {
    u32x4 q; q.x = a; q.y = b; q.z = c4; q.w = d;
    char* dst = (char*)hbuf32 + (size_t)buf * HBYTES
              + ((size_t)(ecol >> 3) * 256 + (size_t)eb * 16);
    asm volatile("global_store_dwordx4 %0, %1, off sc0 sc1" :: "v"(dst), "v"(q) : "memory");
  }
}

// per-WG partial dot(h, w_traj) per batch, from fp32 h (more accurate than bf16
// MFMA path). 16 lanes of one batch tree-reduce; lane ekc==0 stores one float.
// part layout: [parity][batch][wg]  (rows of 64 floats = 256B).
__device__ __forceinline__ void publish_part(float* partbuf, int buf, int wg,
                                             int eb, int ekc,
                                             float h0, float w0, float h1, float w1) {
  float pd = h0 * w0 + h1 * w1;
  pd += __shfl_xor(pd, 1, 64);
  pd += __shfl_xor(pd, 2, 64);
  pd += __shfl_xor(pd, 4, 64);
  pd += __shfl_xor(pd, 8, 64);
  if (ekc == 0) {
    float* dst = partbuf + (size_t)buf * (Bdim * 64) + (size_t)eb * 64 + wg;
    asm volatile("global_store_dword %0, %1, off sc0 sc1" :: "v"(dst), "v"(pd) : "memory");
  }
}

__global__ void __launch_bounds__(TPB, 1) traj_kernel(
    const float* __restrict__ traj_z, const float* __restrict__ traj_input,
    const float* __restrict__ w_ih, const float* __restrict__ b_ih,
    const float* __restrict__ w_hh, const float* __restrict__ b_hh,
    const float* __restrict__ w_traj, const float* __restrict__ b_traj,
    float* __restrict__ out, uint32_t* __restrict__ hbuf32,
    float* __restrict__ partbuf, uint32_t* __restrict__ flags)
{
  const int tid  = threadIdx.x;
  const int wg   = blockIdx.x;
  const int wave = tid >> 6;
  const int lane = tid & 63;
  const int ln16 = lane & 15;
  const int quad = lane >> 4;
  const int colbase = wg * KC;
  const int kwave   = wave * (Hdim / 4);
  const int gcbase  = wave * NCHUNK;       // this wave's first 32-col chunk index

  // LDS: gate-n tile1 B-fragments (64KB) + cross-wave reduction (24KB)
  __shared__ short8_t s_wn1[64][64];             // [gc][lane] = 64 KB
  __shared__ float s_red[4][3][2][16][16];       // wave, gate, tile, m, n = 24 KB

  // ---- build s_wn1 (gate-n, cols colbase+16..+31, all K) ----
  for (int idx = tid; idx < 64 * 64; idx += TPB) {
    const int gc = idx >> 6, l = idx & 63;
    const int col = colbase + 16 + (l & 15);
    const int k0  = gc * 32 + (l >> 4) * 8;
    s_wn1[gc][l] = load8_bf(w_hh + (size_t)(2 * Hdim + col) * Hdim + k0);
  }

  // ---- register-resident B-fragments: 5 arrays (r0,z0,n0,r1,z1) = 320 VGPRs ----
  short8_t fr0[NCHUNK], fz0[NCHUNK], fn0[NCHUNK], fr1[NCHUNK], fz1[NCHUNK];
#pragma unroll
  for (int c = 0; c < NCHUNK; ++c) {
    const int k0 = kwave + c * 32 + quad * 8;
    fr0[c] = load8_bf(w_hh + (size_t)(0 * Hdim + colbase + ln16) * Hdim + k0);
    fz0[c] = load8_bf(w_hh + (size_t)(1 * Hdim + colbase + ln16) * Hdim + k0);
    fn0[c] = load8_bf(w_hh + (size_t)(2 * Hdim + colbase + ln16) * Hdim + k0);
    fr1[c] = load8_bf(w_hh + (size_t)(0 * Hdim + colbase + 16 + ln16) * Hdim + k0);
    fz1[c] = load8_bf(w_hh + (size_t)(1 * Hdim + colbase + 16 + ln16) * Hdim + k0);
  }

  // ---- per-thread epilogue state: thread (eb, ekc) owns cols col0 and col0+16 ----
  const int eb   = tid >> 4;
  const int ekc  = tid & 15;
  const int col0 = colbase + ekc;
  const int col1 = col0 + 16;
  const float wr_0 = w_ih[col0], wz_0 = w_ih[Hdim + col0], wn_0 = w_ih[2 * Hdim + col0];
  const float wr_1 = w_ih[col1], wz_1 = w_ih[Hdim + col1], wn_1 = w_ih[2 * Hdim + col1];
  const float br_0 = b_ih[col0] + b_hh[col0];
  const float bz_0 = b_ih[Hdim + col0] + b_hh[Hdim + col0];
  const float bin_0 = b_ih[2 * Hdim + col0];
  const float bhn_0 = b_hh[2 * Hdim + col0];
  const float br_1 = b_ih[col1] + b_hh[col1];
  const float bz_1 = b_ih[Hdim + col1] + b_hh[Hdim + col1];
  const float bin_1 = b_ih[2 * Hdim + col1];
  const float bhn_1 = b_hh[2 * Hdim + col1];
  const float bt   = b_traj[0];
  const float wtr0 = w_traj[col0], wtr1 = w_traj[col1];
  float h_own0 = traj_z[eb * Hdim + col0];
  float h_own1 = traj_z[eb * Hdim + col1];
  float x_reg  = traj_input[eb * Tsteps];

  // ---- publish h_0 + its w_traj partial ----
  publish_h(hbuf32, 0, eb, ekc, col0, h_own0);
  publish_h(hbuf32, 0, eb, ekc, col1, h_own1);
  publish_part(partbuf, 0, wg, eb, ekc, h_own0, wtr0, h_own1, wtr1);
  publish(flags, wg, tid, 1);

  for (int i = 0; i <= Tsteps; ++i) {
    waitall(flags, tid, (uint32_t)(i + 1));   // all WGs published h_i (+ partials)

    // h_i A-fragments: 16 coalesced uncached 16B loads (unchanged from R3),
    // plus this thread's 16B slice of the partial-dot table — issued together,
    // one vmcnt(0).
    const char* hbase = (const char*)hbuf32 + (size_t)(i & 1) * HBYTES
                      + (size_t)(kwave >> 5) * 1024 + (size_t)lane * 16;
    short8_t af[NCHUNK];
#pragma unroll
    for (int c = 0; c < NCHUNK; ++c) {
      short8_t t;
      asm volatile("global_load_dwordx4 %0, %1, off sc0 sc1"
                   : "=v"(t) : "v"(hbase + (size_t)c * 1024));
      af[c] = t;
    }
    f32x4 pdot;
    {
      const char* pbase = (const char*)partbuf + (size_t)(i & 1) * (Bdim * 64 * 4)
                        + (size_t)eb * 256 + (size_t)ekc * 16;
      asm volatile("global_load_dwordx4 %0, %1, off sc0 sc1"
                   : "=v"(pdot) : "v"(pbase));
    }
    asm volatile("s_waitcnt vmcnt(0)" ::: "memory");
    __builtin_amdgcn_sched_barrier(0);

    f32x4 ar0 = {0.f, 0.f, 0.f, 0.f}, az0 = ar0, an0 = ar0;
    f32x4 ar1 = ar0, az1 = ar0, an1 = ar0;
#pragma unroll
    for (int c = 0; c < NCHUNK; ++c) {
      const short8_t wn1f = s_wn1[gcbase + c][lane];
      ar0 = __builtin_amdgcn_mfma_f32_16x16x32_bf16(af[c], fr0[c], ar0, 0, 0, 0);
      az0 = __builtin_amdgcn_mfma_f32_16x16x32_bf16(af[c], fz0[c], az0, 0, 0, 0);
      an0 = __builtin_amdgcn_mfma_f32_16x16x32_bf16(af[c], fn0[c], an0, 0, 0, 0);
      ar1 = __builtin_amdgcn_mfma_f32_16x16x32_bf16(af[c], fr1[c], ar1, 0, 0, 0);
      az1 = __builtin_amdgcn_mfma_f32_16x16x32_bf16(af[c], fz1[c], az1, 0, 0, 0);
      an1 = __builtin_amdgcn_mfma_f32_16x16x32_bf16(af[c], wn1f,  an1, 0, 0, 0);
    }

    // D[m][n]: n = lane&15, m = quad*4 + r
#pragma unroll
    for (int r = 0; r < 4; ++r) {
      const int m = quad * 4 + r;
      s_red[wave][0][0][m][ln16] = ar0[r]; s_red[wave][0][1][m][ln16] = ar1[r];
      s_red[wave][1][0][m][ln16] = az0[r]; s_red[wave][1][1][m][ln16] = az1[r];
      s_red[wave][2][0][m][ln16] = an0[r]; s_red[wave][2][1][m][ln16] = an1[r];
    }
    __syncthreads();

    // x_i = x_{i-1} + dot(h_i, w_traj) + bt : sum 64 WG partials (4 in-thread
    // + 4-step tree over the 16 lanes of this batch) — identical in all WGs.
    if (i > 0) {
      float S = (pdot[0] + pdot[1]) + (pdot[2] + pdot[3]);
      S += __shfl_xor(S, 1, 64);
      S += __shfl_xor(S, 2, 64);
      S += __shfl_xor(S, 4, 64);
      S += __shfl_xor(S, 8, 64);
      x_reg += S + bt;
      if (wg == 0 && ekc == 0) out[eb * Tsteps + (i - 1)] = x_reg;
    }
    if (i == Tsteps) break;

    // gates for both owned columns
    const float x = x_reg;
    const float gr_0 = ((s_red[0][0][0][eb][ekc] + s_red[1][0][0][eb][ekc]) + s_red[2][0][0][eb][ekc]) + s_red[3][0][0][eb][ekc];
    const float gz_0 = ((s_red[0][1][0][eb][ekc] + s_red[1][1][0][eb][ekc]) + s_red[2][1][0][eb][ekc]) + s_red[3][1][0][eb][ekc];
    const float gn_0 = ((s_red[0][2][0][eb][ekc] + s_red[1][2][0][eb][ekc]) + s_red[2][2][0][eb][ekc]) + s_red[3][2][0][eb][ekc];
    const float gr_1 = ((s_red[0][0][1][eb][ekc] + s_red[1][0][1][eb][ekc]) + s_red[2][0][1][eb][ekc]) + s_red[3][0][1][eb][ekc];
    const float gz_1 = ((s_red[0][1][1][eb][ekc] + s_red[1][1][1][eb][ekc]) + s_red[2][1][1][eb][ekc]) + s_red[3][1][1][eb][ekc];
    const float gn_1 = ((s_red[0][2][1][eb][ekc] + s_red[1][2][1][eb][ekc]) + s_red[2][2][1][eb][ekc]) + s_red[3][2][1][eb][ekc];

    const float rr0 = 1.f / (1.f + expf(-(x * wr_0 + br_0 + gr_0)));
    const float zz0 = 1.f / (1.f + expf(-(x * wz_0 + bz_0 + gz_0)));
    const float nn0 = tanhf(x * wn_0 + bin_0 + rr0 * (gn_0 + bhn_0));
    h_own0 = (1.f - zz0) * nn0 + zz0 * h_own0;

    const float rr1 = 1.f / (1.f + expf(-(x * wr_1 + br_1 + gr_1)));
    const float zz1 = 1.f / (1.f + expf(-(x * wz_1 + bz_1 + gz_1)));
    const float nn1 = tanhf(x * wn_1 + bin_1 + rr1 * (gn_1 + bhn_1));
    h_own1 = (1.f - zz1) * nn1 + zz1 * h_own1;

    // publish h_{i+1} + its partial
    publish_h(hbuf32, (i + 1) & 1, eb, ekc, col0, h_own0);
    publish_h(hbuf32, (i + 1) & 1, eb, ekc, col1, h_own1);
    publish_part(partbuf, (i + 1) & 1, wg, eb, ekc, h_own0, wtr0, h_own1, wtr1);
    publish(flags, wg, tid, (uint32_t)(i + 2));
  }
}

extern "C" void kernel_launch(void* const* d_in, const int* in_sizes, int n_in,
                              void* d_out, int out_size, void* d_ws, size_t ws_size,
                              hipStream_t stream) {
  const float* traj_z     = (const float*)d_in[0];
  const float* traj_input = (const float*)d_in[1];
  const float* w_ih   = (const float*)d_in[2];
  const float* b_ih   = (const float*)d_in[3];
  const float* w_hh   = (const float*)d_in[4];
  const float* b_hh   = (const float*)d_in[5];
  const float* w_traj = (const float*)d_in[6];
  const float* b_traj = (const float*)d_in[7];
  float* out = (float*)d_out;

  uint8_t*  ws    = (uint8_t*)d_ws;
  uint32_t* flags = (uint32_t*)ws;                         // 64*128B = 8 KB (16 KB reserved)
  uint32_t* hbuf  = (uint32_t*)(ws + 16384);               // 2*64KB = 128 KB
  float*    partb = (float*)(ws + 16384 + 2 * HBYTES);     // 2*16*64*4B = 8 KB

  (void)hipMemsetAsync(flags, 0, NWG * FLAGSTRIDE * 4, stream);
  hipLaunchKernelGGL(traj_kernel, dim3(NWG), dim3(TPB), 0, stream,
                     traj_z, traj_input, w_ih, b_ih, w_hh, b_hh, w_traj, b_traj,
                     out, hbuf, partb, flags);
}

// Round 6
// 1680.631 us; speedup vs baseline: 1.5771x; 1.5771x over previous
//
#include <hip/hip_runtime.h>
#include <stdint.h>
#include <math.h>

// Problem constants (B, H, T) = (16, 2048, 512)
#define Hdim   2048
#define Bdim   16
#define Tsteps 512
#define NWG    128   // workgroups; each owns KC columns of h
#define TPB    256   // 4 waves
#define KC     16    // h-columns per WG  (NWG*KC == Hdim)
#define NCHUNK 16    // K-chunks of 32 per wave (wave K-range = 512)
#define FLAGSTRIDE 32  // uint32s between per-WG flags (128B) — separate lines, no store contention
#define HBYTES (Bdim * Hdim * 2)   // one h buffer in bytes (fragment-major bf16)

typedef __attribute__((ext_vector_type(8))) short short8_t;  // 8 bf16 (4 VGPRs)
typedef __attribute__((ext_vector_type(4))) float f32x4;     // MFMA C/D
typedef __attribute__((ext_vector_type(4))) unsigned int u32x4;

__device__ __forceinline__ short f2bf(float x) {
  uint32_t u = __builtin_bit_cast(uint32_t, x);
  u += 0x7fffu + ((u >> 16) & 1u);   // RNE
  return (short)(u >> 16);
}

__device__ __forceinline__ short8_t load8_bf(const float* __restrict__ p) {
  short8_t r;
#pragma unroll
  for (int j = 0; j < 8; ++j) r[j] = f2bf(p[j]);
  return r;
}

// ---- flag barrier helpers ----
// publish: explicit vmcnt(0) drains this wave's h-stores (incl. inline-asm ones
// the compiler doesn't track), __syncthreads joins all waves, then one thread
// stores this WG's arrival flag (own 128B line -> no inter-WG store contention).
__device__ __forceinline__ void publish(uint32_t* flags, int wg, int tid, uint32_t n) {
  asm volatile("s_waitcnt vmcnt(0)" ::: "memory");
  __syncthreads();
  if (tid == 0)
    __hip_atomic_store(flags + wg * FLAGSTRIDE, n, __ATOMIC_RELAXED, __HIP_MEMORY_SCOPE_AGENT);
}

// wait_quarter: wave w only consumes h columns [512w, 512w+512), produced by
// WGs [32w, 32w+32). Poll exactly those 32 SEPARATED flag lines (R2's packed-
// line store contention does not apply) and proceed straight to the loads --
// no block-wide barrier. Buffer-reuse safety: publish() runs __syncthreads()
// BEFORE the flag store, so WG A stores h_{i+1} (overwriting h_{i-1}'s parity)
// only after all 4 of A's waves saw their producer quarters at >= i+1 -- i.e.
// the union = all 128 WGs published h_i, which they do only after their
// step-(i-1) reads of h_{i-1} completed (in-loop vmcnt before their MFMAs).
__device__ __forceinline__ void wait_quarter(const uint32_t* flags, int wave, int lane, uint32_t n) {
  if (lane < 32) {
    const uint32_t* f = flags + (wave * 32 + lane) * FLAGSTRIDE;
    while (__hip_atomic_load(f, __ATOMIC_RELAXED, __HIP_MEMORY_SCOPE_AGENT) < n) {
      __builtin_amdgcn_s_sleep(1);
    }
  }
  __builtin_amdgcn_sched_barrier(0);
}

// ---- h buffer layout (R3): MFMA-fragment-major ----
// 16B block (gc*4 + quad)*16 + batch holds cols [gc*32+quad*8, +8) of one batch.
// Byte offset of (b, col): (col>>3)*256 + b*16 + (col&7)*2.
// Consumer wave reads per chunk a contiguous 1KB span (lane*16B), uncached.
__device__ __forceinline__ void publish_h(uint32_t* hbuf32, int buf,
                                          int eb, int ekc, int ecol, float h_own) {
  uint32_t mybits = (uint32_t)(uint16_t)f2bf(h_own);
  uint32_t n1 = (uint32_t)__shfl_xor((int)mybits, 1, 64);
  uint32_t a  = (mybits & 0xffffu) | (n1 << 16);            // cols j, j+1   (at even j)
  uint32_t b  = (uint32_t)__shfl_xor((int)a, 2, 64);        // cols j+2, j+3 (at j%4==0)
  uint32_t c4 = (uint32_t)__shfl_xor((int)a, 4, 64);        // cols j+4, j+5 (at j%8==0)
  uint32_t d  = (uint32_t)__shfl_xor((int)b, 4, 64);        // cols j+6, j+7 (at j%8==0)
  if ((ekc & 7) == 0) {
    u32x4 q; q.x = a; q.y = b; q.z = c4; q.w = d;
    char* dst = (char*)hbuf32 + (size_t)buf * HBYTES
              + ((size_t)(ecol >> 3) * 256 + (size_t)eb * 16);
    asm volatile("global_store_dwordx4 %0, %1, off sc0 sc1" :: "v"(dst), "v"(q) : "memory");
  }
}

__global__ void __launch_bounds__(TPB, 1) traj_kernel(
    const float* __restrict__ traj_z, const float* __restrict__ traj_input,
    const float* __restrict__ w_ih, const float* __restrict__ b_ih,
    const float* __restrict__ w_hh, const float* __restrict__ b_hh,
    const float* __restrict__ w_traj, const float* __restrict__ b_traj,
    float* __restrict__ out, uint32_t* __restrict__ hbuf32, uint32_t* __restrict__ flags)
{
  const int tid  = threadIdx.x;
  const int wg   = blockIdx.x;
  const int wave = tid >> 6;
  const int lane = tid & 63;
  const int ln16 = lane & 15;       // MFMA: A row (batch) / B col (our 16 rows) / D col
  const int quad = lane >> 4;
  const int colbase = wg * KC;
  const int kwave   = wave * (Hdim / 4);   // this wave's K-quarter

  __shared__ float s_red[4][3][16][16];  // wave, gate-tile, m(batch), n(col)  = 12 KB
  __shared__ float s_x3[4][16];          // per-wave partial dot(h, w_traj) per batch

  // ---- preload w_hh slice as register-resident bf16 B-fragments ----
  // B[k][n]: n = lane&15 (row within tile), k = quad*8 + j within each 32-chunk.
  short8_t wf0[NCHUNK], wf1[NCHUNK], wf2[NCHUNK], wt[NCHUNK];
#pragma unroll
  for (int c = 0; c < NCHUNK; ++c) {
    const int k0 = kwave + c * 32 + quad * 8;
    wf0[c] = load8_bf(w_hh + (size_t)(0 * Hdim + colbase + ln16) * Hdim + k0); // r rows
    wf1[c] = load8_bf(w_hh + (size_t)(1 * Hdim + colbase + ln16) * Hdim + k0); // z rows
    wf2[c] = load8_bf(w_hh + (size_t)(2 * Hdim + colbase + ln16) * Hdim + k0); // n rows
    short8_t g = {0, 0, 0, 0, 0, 0, 0, 0};
    if (ln16 == 0) g = load8_bf(w_traj + k0);    // 4th tile: single w_traj row
    wt[c] = g;
  }

  // ---- per-thread epilogue constants: thread (eb, ekc) owns h[eb][colbase+ekc] ----
  const int eb   = tid >> 4;       // batch 0..15
  const int ekc  = tid & 15;       // col within WG slice
  const int ecol = colbase + ekc;
  const float wr = w_ih[ecol], wz = w_ih[Hdim + ecol], wn = w_ih[2 * Hdim + ecol];
  const float br = b_ih[ecol] + b_hh[ecol];                    // merged r biases
  const float bz = b_ih[Hdim + ecol] + b_hh[Hdim + ecol];      // merged z biases
  const float bin = b_ih[2 * Hdim + ecol];
  const float bhn = b_hh[2 * Hdim + ecol];                     // inside r*(...)
  const float bt  = b_traj[0];
  float h_own = traj_z[eb * Hdim + ecol];                      // fp32 own state
  float x_reg = traj_input[eb * Tsteps];                       // per-thread x for batch eb

  // ---- publish h_0 ----
  publish_h(hbuf32, 0, eb, ekc, ecol, h_own);
  publish(flags, wg, tid, 1);

  // step i: reads h_i, produces h_{i+1}; also dot(h_i, w_traj) -> x_i (i>=1).
  // out[:, i-1] = x_i. Extra iteration i==Tsteps computes only x_T -> out[:,T-1].
  for (int i = 0; i <= Tsteps; ++i) {
    // this wave's K-quarter producers have published h_i
    wait_quarter(flags, wave, lane, (uint32_t)(i + 1));

    // harden vmcnt bookkeeping: everything older is drained, so after issuing
    // the 16 af loads the outstanding count is exactly 16.
    asm volatile("s_waitcnt vmcnt(0)" ::: "memory");

    // A-fragments of h_i: per chunk a contiguous 1KB span (lane*16B), one
    // dwordx4 sc0 sc1 per lane (uncached, reads the coherence point; fully
    // line-coalesced). All 16 issued, then counted-vmcnt groups overlap the
    // MFMA block with the load tail (T4). sched_barrier after each wait is
    // REQUIRED: register-only MFMAs otherwise hoist past inline-asm waits.
    const char* hbase = (const char*)hbuf32 + (size_t)(i & 1) * HBYTES
                      + (size_t)(kwave >> 5) * 1024 + (size_t)lane * 16;
    short8_t af[NCHUNK];
#pragma unroll
    for (int c = 0; c < NCHUNK; ++c) {
      asm volatile("global_load_dwordx4 %0, %1, off sc0 sc1"
                   : "=v"(af[c]) : "v"(hbase + (size_t)c * 1024));
    }

    f32x4 a0 = {0.f, 0.f, 0.f, 0.f}, a1 = a0, a2 = a0, a3 = a0;

#define MFMA_GROUP(G, VM)                                                      \
    asm volatile("s_waitcnt vmcnt(" #VM ")" ::: "memory");                     \
    __builtin_amdgcn_sched_barrier(0);                                         \
    _Pragma("unroll")                                                          \
    for (int c = (G) * 4; c < (G) * 4 + 4; ++c) {                              \
      a0 = __builtin_amdgcn_mfma_f32_16x16x32_bf16(af[c], wf0[c], a0, 0, 0, 0);\
      a1 = __builtin_amdgcn_mfma_f32_16x16x32_bf16(af[c], wf1[c], a1, 0, 0, 0);\
      a2 = __builtin_amdgcn_mfma_f32_16x16x32_bf16(af[c], wf2[c], a2, 0, 0, 0);\
      a3 = __builtin_amdgcn_mfma_f32_16x16x32_bf16(af[c], wt[c],  a3, 0, 0, 0);\
    }

    MFMA_GROUP(0, 12)
    MFMA_GROUP(1, 8)
    MFMA_GROUP(2, 4)
    MFMA_GROUP(3, 0)
#undef MFMA_GROUP

    // D[m][n]: n = lane&15, m = quad*4 + r
#pragma unroll
    for (int r = 0; r < 4; ++r) {
      const int m = quad * 4 + r;
      s_red[wave][0][m][ln16] = a0[r];
      s_red[wave][1][m][ln16] = a1[r];
      s_red[wave][2][m][ln16] = a2[r];
    }
    if (ln16 == 0) {
#pragma unroll
      for (int r = 0; r < 4; ++r) s_x3[wave][quad * 4 + r] = a3[r];
    }
    __syncthreads();

    // x_i = x_{i-1} + dot(h_i, w_traj) + b_traj  (identical arithmetic in every
    // thread of every WG -> bitwise-identical x_reg; no LDS broadcast needed)
    if (i > 0) {
      const float xd = ((s_x3[0][eb] + s_x3[1][eb]) + s_x3[2][eb]) + s_x3[3][eb];
      x_reg += xd + bt;
      if (wg == 0 && ekc == 0) out[eb * Tsteps + (i - 1)] = x_reg;
    }
    if (i == Tsteps) break;

    // gates for (eb, ecol)
    const float gr = ((s_red[0][0][eb][ekc] + s_red[1][0][eb][ekc]) + s_red[2][0][eb][ekc]) + s_red[3][0][eb][ekc];
    const float gz = ((s_red[0][1][eb][ekc] + s_red[1][1][eb][ekc]) + s_red[2][1][eb][ekc]) + s_red[3][1][eb][ekc];
    const float gn = ((s_red[0][2][eb][ekc] + s_red[1][2][eb][ekc]) + s_red[2][2][eb][ekc]) + s_red[3][2][eb][ekc];
    const float x  = x_reg;
    const float rr = 1.f / (1.f + expf(-(x * wr + br + gr)));
    const float zz = 1.f / (1.f + expf(-(x * wz + bz + gz)));
    const float nn = tanhf(x * wn + bin + rr * (gn + bhn));
    h_own = (1.f - zz) * nn + zz * h_own;

    // publish h_{i+1}
    publish_h(hbuf32, (i + 1) & 1, eb, ekc, ecol, h_own);
    publish(flags, wg, tid, (uint32_t)(i + 2));
  }
}

extern "C" void kernel_launch(void* const* d_in, const int* in_sizes, int n_in,
                              void* d_out, int out_size, void* d_ws, size_t ws_size,
                              hipStream_t stream) {
  const float* traj_z     = (const float*)d_in[0];
  const float* traj_input = (const float*)d_in[1];
  const float* w_ih   = (const float*)d_in[2];
  const float* b_ih   = (const float*)d_in[3];
  const float* w_hh   = (const float*)d_in[4];
  const float* b_hh   = (const float*)d_in[5];
  const float* w_traj = (const float*)d_in[6];
  const float* b_traj = (const float*)d_in[7];
  float* out = (float*)d_out;

  uint8_t*  ws    = (uint8_t*)d_ws;
  uint32_t* flags = (uint32_t*)ws;                 // NWG*FLAGSTRIDE u32 = 16 KB
  uint32_t* hbuf  = (uint32_t*)(ws + NWG * FLAGSTRIDE * 4);  // 2*16*2048 bf16 = 128 KB

  (void)hipMemsetAsync(flags, 0, NWG * FLAGSTRIDE * 4, stream);
  hipLaunchKernelGGL(traj_kernel, dim3(NWG), dim3(TPB), 0, stream,
                     traj_z, traj_input, w_ih, b_ih, w_hh, b_hh, w_traj, b_traj,
                     out, hbuf, flags);
}